// Round 6
// baseline (1119.509 us; speedup 1.0000x reference)
//
#include <hip/hip_runtime.h>
#include <cfloat>

#define NB  32
#define ND  256
#define NK  512
#define NHW 4096
#define PX  16
#define ZSTR (ND + 4)     // 260 floats; rows 16B-aligned
#define MARGIN 1.3e-4f    // >= 2 ulps for any X < 1024; fast-vs-np diff <= 1 ulp

// C declared int64 in the reference; detect storage width on device.
__device__ __forceinline__ int loadC(const int* __restrict__ C, int b) {
  int orodd = 0;
#pragma unroll
  for (int i = 1; i < 32; i += 2) orodd |= C[i];
  return (orodd == 0) ? C[2 * b] : C[b];
}

// np.sum pairwise block (n=128) on fl(z*z) — verbatim from the passing R5 kernel.
__device__ __forceinline__ float pwsq128(const float* __restrict__ a) {
  float r[8];
#pragma unroll
  for (int j = 0; j < 8; ++j) r[j] = __fmul_rn(a[j], a[j]);
  for (int i = 8; i < 128; i += 8)
#pragma unroll
    for (int j = 0; j < 8; ++j)
      r[j] = __fadd_rn(r[j], __fmul_rn(a[i + j], a[i + j]));
  return __fadd_rn(
      __fadd_rn(__fadd_rn(r[0], r[1]), __fadd_rn(r[2], r[3])),
      __fadd_rn(__fadd_rn(r[4], r[5]), __fadd_rn(r[6], r[7])));
}

// Exact np-replica score for one (pixel,code) — verbatim op order from R5.
__device__ float np_score(const float* __restrict__ zrow,
                          const float* __restrict__ er, float S) {
  float P0 = 0.f, P1 = 0.f, P2 = 0.f, P3 = 0.f;
  for (int ch = 0; ch < 16; ++ch) {
    const float* eb = er + ch * 16;
    float4 e0 = *(const float4*)(eb + 0);
    float4 e1 = *(const float4*)(eb + 4);
    float4 e2 = *(const float4*)(eb + 8);
    float4 e3 = *(const float4*)(eb + 12);
    const float* zb = zrow + ch * 16;
    float4 z0 = *(const float4*)(zb + 0);
    float4 z1 = *(const float4*)(zb + 4);
    float4 z2 = *(const float4*)(zb + 8);
    float4 z3 = *(const float4*)(zb + 12);
    P0 = __fadd_rn(P0, __fmul_rn(z3.x, e3.x));
    P0 = __fadd_rn(P0, __fmul_rn(z2.x, e2.x));
    P0 = __fadd_rn(P0, __fmul_rn(z1.x, e1.x));
    P0 = __fadd_rn(P0, __fmul_rn(z0.x, e0.x));
    P1 = __fadd_rn(P1, __fmul_rn(z3.y, e3.y));
    P1 = __fadd_rn(P1, __fmul_rn(z2.y, e2.y));
    P1 = __fadd_rn(P1, __fmul_rn(z1.y, e1.y));
    P1 = __fadd_rn(P1, __fmul_rn(z0.y, e0.y));
    P2 = __fadd_rn(P2, __fmul_rn(z3.z, e3.z));
    P2 = __fadd_rn(P2, __fmul_rn(z2.z, e2.z));
    P2 = __fadd_rn(P2, __fmul_rn(z1.z, e1.z));
    P2 = __fadd_rn(P2, __fmul_rn(z0.z, e0.z));
    P3 = __fadd_rn(P3, __fmul_rn(z3.w, e3.w));
    P3 = __fadd_rn(P3, __fmul_rn(z2.w, e2.w));
    P3 = __fadd_rn(P3, __fmul_rn(z1.w, e1.w));
    P3 = __fadd_rn(P3, __fmul_rn(z0.w, e0.w));
  }
  float G = __fadd_rn(__fadd_rn(P0, P1), __fadd_rn(P2, P3));
  return __fadd_rn(S, __fmul_rn(-2.0f, G));
}

__global__ __launch_bounds__(256, 3) void k_fused2(
    const float* __restrict__ z, const int* __restrict__ Cc,
    const float* __restrict__ w, float* __restrict__ out) {
  __shared__ float Zs[PX][ZSTR];       // 16.6 KB
  __shared__ float Xs[NK * PX];        // 32 KB: fast score per (code,pixel)
  __shared__ float Ssh[PX];
  __shared__ float SVmin[4][PX];
  __shared__ float SVv[4][PX];
  __shared__ int   SVi[4][PX];
  __shared__ float Thr[PX];
  __shared__ int   KB[PX];

  int blk = blockIdx.x;                // 8192 = 32 batches x 256 tiles
  int b   = blk >> 8;
  int n0  = (blk & 255) * PX;
  int c   = loadC(Cc, b);
  int t   = threadIdx.x;
  int lane = t & 63, wv = t >> 6;

  // ---- stage z tile [16 px][256 d] (verbatim R5) ----
  {
    int px = t & 15, tg = t >> 4;
    const float* zp = z + (size_t)b * ND * NHW + n0 + px;
#pragma unroll
    for (int j = 0; j < 16; ++j) {
      int d = tg * 16 + j;
      Zs[px][d] = zp[(size_t)d * NHW];
    }
  }
  __syncthreads();

  // ---- S[px]: np pairwise replica (verbatim R5) ----
  if (t < PX)
    Ssh[t] = __fadd_rn(pwsq128(&Zs[t][0]), pwsq128(&Zs[t][128]));
  __syncthreads();

  // ---- fast pass (FMA): thread t scores codes t and t+256 for 16 px ----
  const float4* e0p = (const float4*)(w + ((size_t)c * NK + t) * ND);
  const float4* e1p = (const float4*)(w + ((size_t)c * NK + t + 256) * ND);
  float acc0[PX], acc1[PX];
#pragma unroll
  for (int p = 0; p < PX; ++p) { acc0[p] = 0.f; acc1[p] = 0.f; }

  for (int ch = 0; ch < 16; ++ch) {
    float4 a0 = e0p[ch * 4 + 0], a1 = e0p[ch * 4 + 1];
    float4 a2 = e0p[ch * 4 + 2], a3 = e0p[ch * 4 + 3];
    float4 b0 = e1p[ch * 4 + 0], b1 = e1p[ch * 4 + 1];
    float4 b2 = e1p[ch * 4 + 2], b3 = e1p[ch * 4 + 3];
#pragma unroll
    for (int p = 0; p < PX; ++p) {
      const float* zb = &Zs[p][ch * 16];
      float4 z0 = *(const float4*)(zb + 0);
      float4 z1 = *(const float4*)(zb + 4);
      float4 z2 = *(const float4*)(zb + 8);
      float4 z3 = *(const float4*)(zb + 12);
      float s0 = acc0[p], s1 = acc1[p];
      s0 = fmaf(z0.x, a0.x, s0); s1 = fmaf(z0.x, b0.x, s1);
      s0 = fmaf(z0.y, a0.y, s0); s1 = fmaf(z0.y, b0.y, s1);
      s0 = fmaf(z0.z, a0.z, s0); s1 = fmaf(z0.z, b0.z, s1);
      s0 = fmaf(z0.w, a0.w, s0); s1 = fmaf(z0.w, b0.w, s1);
      s0 = fmaf(z1.x, a1.x, s0); s1 = fmaf(z1.x, b1.x, s1);
      s0 = fmaf(z1.y, a1.y, s0); s1 = fmaf(z1.y, b1.y, s1);
      s0 = fmaf(z1.z, a1.z, s0); s1 = fmaf(z1.z, b1.z, s1);
      s0 = fmaf(z1.w, a1.w, s0); s1 = fmaf(z1.w, b1.w, s1);
      s0 = fmaf(z2.x, a2.x, s0); s1 = fmaf(z2.x, b2.x, s1);
      s0 = fmaf(z2.y, a2.y, s0); s1 = fmaf(z2.y, b2.y, s1);
      s0 = fmaf(z2.z, a2.z, s0); s1 = fmaf(z2.z, b2.z, s1);
      s0 = fmaf(z2.w, a2.w, s0); s1 = fmaf(z2.w, b2.w, s1);
      s0 = fmaf(z3.x, a3.x, s0); s1 = fmaf(z3.x, b3.x, s1);
      s0 = fmaf(z3.y, a3.y, s0); s1 = fmaf(z3.y, b3.y, s1);
      s0 = fmaf(z3.z, a3.z, s0); s1 = fmaf(z3.z, b3.z, s1);
      s0 = fmaf(z3.w, a3.w, s0); s1 = fmaf(z3.w, b3.w, s1);
      acc0[p] = s0; acc1[p] = s1;
    }
  }

  // fast scores with np-identical final rounding; per-pixel wave min
#pragma unroll
  for (int p = 0; p < PX; ++p) {
    float X0 = __fadd_rn(Ssh[p], __fmul_rn(-2.0f, acc0[p]));
    float X1 = __fadd_rn(Ssh[p], __fmul_rn(-2.0f, acc1[p]));
    Xs[t * PX + p] = X0;
    Xs[(t + 256) * PX + p] = X1;
    float m = fminf(X0, X1);
#pragma unroll
    for (int off = 32; off; off >>= 1) m = fminf(m, __shfl_down(m, off));
    if (lane == 0) SVmin[wv][p] = m;
  }
  __syncthreads();
  if (t < PX)
    Thr[t] = fminf(fminf(SVmin[0][t], SVmin[1][t]),
                   fminf(SVmin[2][t], SVmin[3][t])) + MARGIN;
  __syncthreads();

  // ---- exact pass: re-score candidates with np-replica, argmin (ties->low k) ----
  const float* er0 = w + ((size_t)c * NK + t) * ND;
  const float* er1 = er0 + (size_t)256 * ND;
  for (int p = 0; p < PX; ++p) {
    float thr = Thr[p];
    float S = Ssh[p];
    float bv = FLT_MAX; int bi = 0x7fffffff;
    if (Xs[t * PX + p] <= thr) { bv = np_score(&Zs[p][0], er0, S); bi = t; }
    if (Xs[(t + 256) * PX + p] <= thr) {
      float v = np_score(&Zs[p][0], er1, S);
      if (v < bv) { bv = v; bi = t + 256; }     // strict <: ties keep lower k
    }
#pragma unroll
    for (int off = 32; off; off >>= 1) {
      float ov = __shfl_down(bv, off);
      int   oi = __shfl_down(bi, off);
      if (ov < bv || (ov == bv && oi < bi)) { bv = ov; bi = oi; }
    }
    if (lane == 0) { SVv[wv][p] = bv; SVi[wv][p] = bi; }
  }
  __syncthreads();
  if (t < PX) {
    float v = SVv[0][t]; int i = SVi[0][t];
#pragma unroll
    for (int wv2 = 1; wv2 < 4; ++wv2) {
      float ov = SVv[wv2][t]; int oi = SVi[wv2][t];
      if (ov < v || (ov == v && oi < i)) { v = ov; i = oi; }
    }
    KB[t] = i;
  }
  __syncthreads();

  // ---- gather + transpose-write both outputs (verbatim R5) ----
  {
    int px = t & 15, tg = t >> 4;
    int kidx = KB[px];
    const float* er = w + ((size_t)c * NK + kidx) * ND;
    const size_t OUT2 = (size_t)NB * ND * NHW;
    size_t base = (size_t)b * ND * NHW + n0 + px;
#pragma unroll
    for (int j = 0; j < 16; ++j) {
      int d = tg * 16 + j;
      float q  = er[d];
      float zv = Zs[px][d];
      out[base + (size_t)d * NHW]        = __fadd_rn(zv, __fsub_rn(q, zv));
      out[base + (size_t)d * NHW + OUT2] = q;
    }
  }
}

extern "C" void kernel_launch(void* const* d_in, const int* in_sizes, int n_in,
                              void* d_out, int out_size, void* d_ws, size_t ws_size,
                              hipStream_t stream) {
  const float* z = (const float*)d_in[0];
  const int*   C = (const int*)d_in[1];
  const float* w = (const float*)d_in[2];
  float* out = (float*)d_out;
  k_fused2<<<NB * (NHW / PX), 256, 0, stream>>>(z, C, w, out);
}